// Round 13
// baseline (265.583 us; speedup 1.0000x reference)
//
#include <hip/hip_runtime.h>

typedef __bf16 bf16x8 __attribute__((ext_vector_type(8)));
typedef float f32x16 __attribute__((ext_vector_type(16)));

// global -> LDS direct copy: per-lane 16 B from gsrc(+lane*16 by caller),
// written at wave-uniform ldst + lane*16. size must be literal 16.
#define GLOAD_LDS16(gsrc, ldst)                                                   \
  __builtin_amdgcn_global_load_lds(                                               \
      (const __attribute__((address_space(1))) void*)(gsrc),                      \
      (__attribute__((address_space(3))) void*)(ldst), 16, 0, 0)

// ---------------------------------------------------------------------------
// Generic fragment pack: W[K][512] f32 row-major -> bf16 MFMA-frag order
//   P[((c*KB + kb)*64 + l)*8 + e] = W[kb*16 + (l>>5)*8 + e][c*32 + (l&31)]
// ---------------------------------------------------------------------------
__device__ __forceinline__ void pack_one(const float* __restrict__ src,
                                         __bf16* __restrict__ dst,
                                         int t, int kbshift) {
  int e = t & 7, l = (t >> 3) & 63;
  int kb = (t >> 9) & ((1 << kbshift) - 1);
  int c = t >> (9 + kbshift);
  int k = kb * 16 + ((l >> 5) << 3) + e;
  int n = (c << 5) + (l & 31);
  dst[t] = (__bf16)src[k * 512 + n];
}

__global__ __launch_bounds__(256) void pack_all(
    const float* __restrict__ Wcb, const float* __restrict__ Wcc,
    const float* __restrict__ Wb, const float* __restrict__ Wca,
    const float* __restrict__ Wa,
    __bf16* __restrict__ Pb, __bf16* __restrict__ Pc,
    __bf16* __restrict__ PWb, __bf16* __restrict__ PH0,
    __bf16* __restrict__ PH1, __bf16* __restrict__ PWa) {
  int idx = blockIdx.x * 256 + threadIdx.x;           // 0 .. 1441791
  if (idx < 262144) {
    pack_one(Wcb, Pb, idx, 5);
  } else if (idx < 524288) {
    pack_one(Wcc, Pc, idx - 262144, 5);
  } else if (idx < 786432) {
    pack_one(Wb, PWb, idx - 524288, 5);
  } else if (idx < 1048576) {
    pack_one(Wca, PH0, idx - 786432, 5);
  } else if (idx < 1310720) {
    pack_one(Wca + 512 * 512, PH1, idx - 1048576, 5);
  } else if (idx < 1441792) {
    pack_one(Wa, PWa, idx - 1310720, 4);              // K=256 -> KB=16
  }
}

// ---------------------------------------------------------------------------
// Node MFMA GEMM: C[1024,512] = act(A[1024,K] @ W + bias), W pre-packed bf16.
// ---------------------------------------------------------------------------
template <int K>
__global__ __launch_bounds__(512, 2) void node_mfma(
    const float* __restrict__ A, const bf16x8* __restrict__ P0,
    const bf16x8* __restrict__ P1, const float* __restrict__ bias,
    int do_relu, float* __restrict__ C0, float* __restrict__ C1) {
  constexpr int KB = K / 16;                 // kb-steps
  constexpr int KH = K / 2;                  // col-pairs per row
  __shared__ __align__(16) char sA[64 * K * 2];

  int row0 = blockIdx.x * 64;
  const bf16x8* P = blockIdx.y ? P1 : P0;
  float* C = blockIdx.y ? C1 : C0;
  int tid = threadIdx.x, lane = tid & 63, w = tid >> 6;

  // ---- stage A tile: fp32 -> bf16, swizzled ----
  {
    int k2 = tid & (KH - 1);                 // fixed col-pair
    int rof = tid / KH;                      // row offset within iter
    constexpr int RPI = 512 / KH;            // rows per iteration
#pragma unroll 4
    for (int it = 0; it < 64 / RPI; it++) {
      int r = it * RPI + rof;
      float2 aa = *(const float2*)(A + (row0 + r) * K + 2 * k2);
      unsigned short s0 = __builtin_bit_cast(unsigned short, (__bf16)aa.x);
      unsigned short s1 = __builtin_bit_cast(unsigned short, (__bf16)aa.y);
      unsigned int pk = ((unsigned int)s1 << 16) | (unsigned int)s0;
      int wbyte = r * (2 * K) + ((4 * k2) ^ ((r & 15) << 4));
      *(unsigned int*)(sA + wbyte) = pk;
    }
  }
  __syncthreads();

  int mrow = (w & 1) * 32;
  int n0 = (w >> 1) * 128;
  int cg4 = (w >> 1) * 4;
  int arow = mrow + (lane & 31);
  int sAk = (arow & 15) << 4;
  int klo = (lane >> 5) * 8;

  const bf16x8* B0 = P + ((cg4 + 0) * KB) * 64 + lane;
  const bf16x8* B1 = P + ((cg4 + 1) * KB) * 64 + lane;
  const bf16x8* B2 = P + ((cg4 + 2) * KB) * 64 + lane;
  const bf16x8* B3 = P + ((cg4 + 3) * KB) * 64 + lane;

  f32x16 acc[4];
#pragma unroll
  for (int nb = 0; nb < 4; nb++)
#pragma unroll
    for (int r = 0; r < 16; r++) acc[nb][r] = 0.f;

#pragma unroll 2
  for (int kb = 0; kb < KB; kb++) {
    int abyte = arow * (2 * K) + (((kb * 16 + klo) * 2) ^ sAk);
    bf16x8 a = *(const bf16x8*)(sA + abyte);
    bf16x8 b0 = B0[kb * 64];
    bf16x8 b1 = B1[kb * 64];
    bf16x8 b2 = B2[kb * 64];
    bf16x8 b3 = B3[kb * 64];
    acc[0] = __builtin_amdgcn_mfma_f32_32x32x16_bf16(a, b0, acc[0], 0, 0, 0);
    acc[1] = __builtin_amdgcn_mfma_f32_32x32x16_bf16(a, b1, acc[1], 0, 0, 0);
    acc[2] = __builtin_amdgcn_mfma_f32_32x32x16_bf16(a, b2, acc[2], 0, 0, 0);
    acc[3] = __builtin_amdgcn_mfma_f32_32x32x16_bf16(a, b3, acc[3], 0, 0, 0);
  }

  // ---- epilogue: bias / relu, fp32 store ----
#pragma unroll
  for (int nb = 0; nb < 4; nb++) {
    int cn = n0 + nb * 32 + (lane & 31);
    float bv = bias ? bias[cn] : 0.f;
#pragma unroll
    for (int r = 0; r < 16; r++) {
      int rr = mrow + (r & 3) + 8 * (r >> 2) + 4 * (lane >> 5);
      float val = acc[nb][r] + bv;
      if (do_relu) val = fmaxf(val, 0.f);
      C[(row0 + rr) * 512 + cn] = val;
    }
  }
}

// ---------------------------------------------------------------------------
// Fused edge kernel — BARRIERLESS counted-vmcnt private B ring (r10 retry).
// r13 deltas vs r10: NO sched_barrier(0) anywhere (m141 order-pin removed;
// asm "memory" clobbers alone order the memory ops), NO epilogue-constant
// preloads (kill the register-pressure spill).
// One WG = (b, i, 64 j). h tile 64 KB @0; B ring 4 slots x 16 KB @65536
// (128 KB LDS). Wave w owns col-blocks {2w,2w+1}; ring region wave-private.
// Stage distance 3: entry to step kb has 6 loads in flight; issue
// STAGE(kb+3) -> 8; vmcnt(6) drains kb's pair (FIFO). Tail 4/2/0.
// Cross-wave sync: 4 phase barriers only (raw s_barrier + lgkmcnt asm;
// no vmcnt drain so prefetch flies across).
// ---------------------------------------------------------------------------
__global__ __launch_bounds__(512, 2) void edge_kernel(
    const float* __restrict__ u, const float* __restrict__ v,
    const bf16x8* __restrict__ Pb, const bf16x8* __restrict__ Pc,
    const float* __restrict__ bca, const float* __restrict__ bcb,
    const float* __restrict__ bcc, const float* __restrict__ Wo,
    const float* __restrict__ bo, float* __restrict__ out) {
  __shared__ __align__(16) char h_raw[131072];
  char* Bst = h_raw + 65536;

  int wg = blockIdx.x;                 // ((b*128 + i)*2 + jh)
  int jh = wg & 1, i = (wg >> 1) & 127, b = wg >> 8;
  int j0 = jh * 64;
  int tid = threadIdx.x, lane = tid & 63, w = tid >> 6;

  int cb0 = 2 * w;                     // this wave's two col-blocks
  int r0 = lane & 31;                  // row within row-group
  int sA = (r0 & 15) << 4;             // A swizzle key ((r0+32)&15 == r0&15)
  int klo = (lane >> 5) * 8;

#define STAGE_B(P, kb, slot)                                                      \
  {                                                                               \
    const char* g0_ = (const char*)((P) + ((cb0) * 32 + (kb)) * 64) + lane * 16;  \
    const char* g1_ = (const char*)((P) + ((cb0 + 1) * 32 + (kb)) * 64) + lane * 16; \
    GLOAD_LDS16(g0_, Bst + (slot) * 16384 + (cb0) * 1024);                        \
    GLOAD_LDS16(g1_, Bst + (slot) * 16384 + (cb0 + 1) * 1024);                    \
  }

#define KSTEP(P, kb, DO_STAGE, VMSTR)                                             \
  {                                                                               \
    if (DO_STAGE) STAGE_B(P, (kb) + 3, ((kb) + 3) & 3)                            \
    asm volatile("s_waitcnt vmcnt(" VMSTR ")" ::: "memory");                      \
    const char* bb_ = Bst + ((kb) & 3) * 16384 + lane * 16;                       \
    bf16x8 b0 = *(const bf16x8*)(bb_ + cb0 * 1024);                               \
    bf16x8 b1 = *(const bf16x8*)(bb_ + (cb0 + 1) * 1024);                         \
    int ab_ = (((kb) * 16 + klo) * 2) ^ sA;                                       \
    bf16x8 a0 = *(const bf16x8*)(h_raw + r0 * 1024 + ab_);                        \
    bf16x8 a1 = *(const bf16x8*)(h_raw + (r0 + 32) * 1024 + ab_);                 \
    __builtin_amdgcn_s_setprio(1);                                                \
    accA0 = __builtin_amdgcn_mfma_f32_32x32x16_bf16(a0, b0, accA0, 0, 0, 0);      \
    accA1 = __builtin_amdgcn_mfma_f32_32x32x16_bf16(a0, b1, accA1, 0, 0, 0);      \
    accB0 = __builtin_amdgcn_mfma_f32_32x32x16_bf16(a1, b0, accB0, 0, 0, 0);      \
    accB1 = __builtin_amdgcn_mfma_f32_32x32x16_bf16(a1, b1, accB1, 0, 0, 0);      \
    __builtin_amdgcn_s_setprio(0);                                                \
  }

  // ---- phase 1: h1 = relu(u[j] + v[i] + bca) for the 64 j's ----
  {
    int k2 = tid & 255;                                    // fixed col-pair
    float2 vv = *(const float2*)(v + (b * 128 + i) * 512 + 2 * k2);
    float2 bc = *(const float2*)(bca + 2 * k2);
    float vb0 = vv.x + bc.x, vb1 = vv.y + bc.y;
    const float* ub = u + (b * 128 + j0) * 512;
#pragma unroll 4
    for (int it = 0; it < 32; it++) {
      int r = it * 2 + (tid >> 8);
      float2 uu = *(const float2*)(ub + r * 512 + 2 * k2);
      float x0 = fmaxf(uu.x + vb0, 0.f);
      float x1 = fmaxf(uu.y + vb1, 0.f);
      unsigned short s0 = __builtin_bit_cast(unsigned short, (__bf16)x0);
      unsigned short s1 = __builtin_bit_cast(unsigned short, (__bf16)x1);
      unsigned int pk = ((unsigned int)s1 << 16) | (unsigned int)s0;
      int wbyte = r * 1024 + ((4 * k2) ^ ((r & 15) << 4));
      *(unsigned int*)(h_raw + wbyte) = pk;
    }
  }

  f32x16 accA0, accA1, accB0, accB1;
#pragma unroll
  for (int r = 0; r < 16; r++) { accA0[r] = 0.f; accA1[r] = 0.f; accB0[r] = 0.f; accB1[r] = 0.f; }

  // ---- GEMM 1 prologue: stage kb=0,1,2 (in flight across the barrier) ----
  STAGE_B(Pb, 0, 0)
  STAGE_B(Pb, 1, 1)
  STAGE_B(Pb, 2, 2)
  asm volatile("s_waitcnt lgkmcnt(0)" ::: "memory");   // h1 stores retired
  __builtin_amdgcn_s_barrier();                        // h1 ready everywhere

  // ---- GEMM 1: h2 = h1 @ Wcb (barrierless, counted vmcnt) ----
  for (int kb = 0; kb < 29; kb++) KSTEP(Pb, kb, 1, "6")
  KSTEP(Pb, 29, 0, "4")
  KSTEP(Pb, 30, 0, "2")
  KSTEP(Pb, 31, 0, "0")

  // ---- GEMM 2 prologue: stage Pc kb=0,1,2 (fly across epilogue 1) ----
  STAGE_B(Pc, 0, 0)
  STAGE_B(Pc, 1, 1)
  STAGE_B(Pc, 2, 2)
  asm volatile("s_waitcnt lgkmcnt(0)" ::: "memory");
  __builtin_amdgcn_s_barrier();                        // all h1 reads done

  // ---- epilogue 1: h2 = relu(acc + bcb) -> bf16 LDS (swizzled) ----
#pragma unroll
  for (int blk = 0; blk < 2; blk++) {
    int cn = cb0 * 32 + blk * 32 + (lane & 31);
    float bbv = bcb[cn];
    const f32x16& A0 = blk ? accA1 : accA0;
    const f32x16& A1 = blk ? accB1 : accB0;
#pragma unroll
    for (int r = 0; r < 16; r++) {
      int crow = (r & 3) + 8 * (r >> 2) + 4 * (lane >> 5);
      int byte_ = crow * 1024 + ((cn * 2) ^ ((crow & 15) << 4));
      *(__bf16*)(h_raw + byte_) = (__bf16)fmaxf(A0[r] + bbv, 0.f);
      *(__bf16*)(h_raw + byte_ + 32 * 1024) = (__bf16)fmaxf(A1[r] + bbv, 0.f);
    }
  }
#pragma unroll
  for (int r = 0; r < 16; r++) { accA0[r] = 0.f; accA1[r] = 0.f; accB0[r] = 0.f; accB1[r] = 0.f; }
  asm volatile("s_waitcnt lgkmcnt(0)" ::: "memory");   // h2 stores retired
  __builtin_amdgcn_s_barrier();                        // h2 ready everywhere

  // ---- GEMM 2: h3 = h2 @ Wcc (barrierless, counted vmcnt) ----
  for (int kb = 0; kb < 29; kb++) KSTEP(Pc, kb, 1, "6")
  KSTEP(Pc, 29, 0, "4")
  KSTEP(Pc, 30, 0, "2")
  KSTEP(Pc, 31, 0, "0")

  __syncthreads();                 // all GEMM2 LDS reads done; reuse h_raw
  float* red = (float*)h_raw;      // [8 waves][64 rows][2] = 4 KB

  // ---- epilogue 2: per row-group, h3 = relu(acc+bcc); fold Wo; shfl-reduce ----
#pragma unroll
  for (int rg = 0; rg < 2; rg++) {
    float p[16][2];
#pragma unroll
    for (int r = 0; r < 16; r++) { p[r][0] = 0.f; p[r][1] = 0.f; }
#pragma unroll
    for (int blk = 0; blk < 2; blk++) {
      int cn = cb0 * 32 + blk * 32 + (lane & 31);
      float bcv = bcc[cn];
      float2 wov = *(const float2*)(Wo + cn * 2);
      const f32x16& A = rg ? (blk ? accB1 : accB0) : (blk ? accA1 : accA0);
#pragma unroll
      for (int r = 0; r < 16; r++) {
        float h3 = fmaxf(A[r] + bcv, 0.f);
        p[r][0] += h3 * wov.x;
        p[r][1] += h3 * wov.y;
      }
    }
#pragma unroll
    for (int m = 1; m <= 16; m <<= 1) {
#pragma unroll
      for (int r = 0; r < 16; r++) {
        p[r][0] += __shfl_xor(p[r][0], m, 64);
        p[r][1] += __shfl_xor(p[r][1], m, 64);
      }
    }
    if ((lane & 31) == 0) {
      int hh = lane >> 5;
#pragma unroll
      for (int r = 0; r < 16; r++) {
        int crow = (r & 3) + 8 * (r >> 2) + 4 * hh;
        red[(w * 64 + rg * 32 + crow) * 2 + 0] = p[r][0];
        red[(w * 64 + rg * 32 + crow) * 2 + 1] = p[r][1];
      }
    }
  }
  __syncthreads();
  if (tid < 128) {
    int row = tid >> 1, d = tid & 1;
    float s = bo[d];
#pragma unroll
    for (int ww = 0; ww < 8; ww++) s += red[(ww * 64 + row) * 2 + d];
    out[(((b * 128 + i) * 128) + j0 + row) * 2 + d] = s;
  }
#undef KSTEP
#undef STAGE_B
}

// ---------------------------------------------------------------------------
extern "C" void kernel_launch(void* const* d_in, const int* in_sizes, int n_in,
                              void* d_out, int out_size, void* d_ws, size_t ws_size,
                              hipStream_t stream) {
  const float* x   = (const float*)d_in[0];
  const float* Wa  = (const float*)d_in[1];
  const float* ba  = (const float*)d_in[2];
  const float* Wb  = (const float*)d_in[3];
  const float* bb  = (const float*)d_in[4];
  const float* Wca = (const float*)d_in[5];
  const float* bca = (const float*)d_in[6];
  const float* Wcb = (const float*)d_in[7];
  const float* bcb = (const float*)d_in[8];
  const float* Wcc = (const float*)d_in[9];
  const float* bcc = (const float*)d_in[10];
  const float* Wo  = (const float*)d_in[11];
  const float* bo  = (const float*)d_in[12];
  float* out = (float*)d_out;

  char* ws = (char*)d_ws;
  float* f1 = (float*)(ws);                                 // 2 MB
  float* f  = (float*)(ws + (2u << 20));                    // 2 MB
  float* u  = (float*)(ws + (4u << 20));                    // 2 MB
  float* v  = (float*)(ws + (6u << 20));                    // 2 MB
  __bf16* Pb  = (__bf16*)(ws + (8u << 20));                 // 512 KB
  __bf16* Pc  = (__bf16*)(ws + (8u << 20) + (512u << 10));  // 512 KB
  __bf16* PWb = (__bf16*)(ws + (9u << 20));                 // 512 KB
  __bf16* PH0 = (__bf16*)(ws + (9u << 20) + (512u << 10));  // 512 KB
  __bf16* PH1 = (__bf16*)(ws + (10u << 20));                // 512 KB
  __bf16* PWa = (__bf16*)(ws + (10u << 20) + (512u << 10)); // 256 KB

  pack_all<<<5632, 256, 0, stream>>>(Wcb, Wcc, Wb, Wca, Wa,
                                     Pb, Pc, PWb, PH0, PH1, PWa);
  node_mfma<256><<<dim3(16, 1), 512, 0, stream>>>(
      x, (const bf16x8*)PWa, (const bf16x8*)PWa, ba, 1, f1, f1);
  node_mfma<512><<<dim3(16, 1), 512, 0, stream>>>(
      f1, (const bf16x8*)PWb, (const bf16x8*)PWb, bb, 1, f, f);
  node_mfma<512><<<dim3(16, 2), 512, 0, stream>>>(
      f, (const bf16x8*)PH0, (const bf16x8*)PH1, nullptr, 0, u, v);
  edge_kernel<<<2048, 512, 0, stream>>>(u, v, (const bf16x8*)Pb, (const bf16x8*)Pc,
                                        bca, bcb, bcc, Wo, bo, out);
}

// Round 14
// 217.322 us; speedup vs baseline: 1.2221x; 1.2221x over previous
//
#include <hip/hip_runtime.h>

typedef __bf16 bf16x8 __attribute__((ext_vector_type(8)));
typedef float f32x16 __attribute__((ext_vector_type(16)));

// global -> LDS direct copy: per-lane 16 B from gsrc(+lane*16 by caller),
// written at wave-uniform ldst + lane*16. size must be literal 16.
#define GLOAD_LDS16(gsrc, ldst)                                                   \
  __builtin_amdgcn_global_load_lds(                                               \
      (const __attribute__((address_space(1))) void*)(gsrc),                      \
      (__attribute__((address_space(3))) void*)(ldst), 16, 0, 0)

// ---------------------------------------------------------------------------
// Generic fragment pack: W[K][512] f32 row-major -> bf16 MFMA-frag order
//   P[((c*KB + kb)*64 + l)*8 + e] = W[kb*16 + (l>>5)*8 + e][c*32 + (l&31)]
// ---------------------------------------------------------------------------
__device__ __forceinline__ void pack_one(const float* __restrict__ src,
                                         __bf16* __restrict__ dst,
                                         int t, int kbshift) {
  int e = t & 7, l = (t >> 3) & 63;
  int kb = (t >> 9) & ((1 << kbshift) - 1);
  int c = t >> (9 + kbshift);
  int k = kb * 16 + ((l >> 5) << 3) + e;
  int n = (c << 5) + (l & 31);
  dst[t] = (__bf16)src[k * 512 + n];
}

__global__ __launch_bounds__(256) void pack_all(
    const float* __restrict__ Wcb, const float* __restrict__ Wcc,
    const float* __restrict__ Wb, const float* __restrict__ Wca,
    const float* __restrict__ Wa,
    __bf16* __restrict__ Pb, __bf16* __restrict__ Pc,
    __bf16* __restrict__ PWb, __bf16* __restrict__ PH0,
    __bf16* __restrict__ PH1, __bf16* __restrict__ PWa) {
  int idx = blockIdx.x * 256 + threadIdx.x;           // 0 .. 1441791
  if (idx < 262144) {
    pack_one(Wcb, Pb, idx, 5);
  } else if (idx < 524288) {
    pack_one(Wcc, Pc, idx - 262144, 5);
  } else if (idx < 786432) {
    pack_one(Wb, PWb, idx - 524288, 5);
  } else if (idx < 1048576) {
    pack_one(Wca, PH0, idx - 786432, 5);
  } else if (idx < 1310720) {
    pack_one(Wca + 512 * 512, PH1, idx - 1048576, 5);
  } else if (idx < 1441792) {
    pack_one(Wa, PWa, idx - 1310720, 4);              // K=256 -> KB=16
  }
}

// ---------------------------------------------------------------------------
// Node MFMA GEMM, 32-row tiles for 2x grid parallelism (launch-latency trim).
// C[1024,512] = act(A[1024,K] @ W + bias), W pre-packed bf16.
// 8 waves share rows 0..31; wave w owns col-blocks {2w, 2w+1} (64 cols).
// Same fragment math / epilogue mapping as the proven 64-row version
// restricted to mrow=0 -> identical per-output MFMA sequence.
// grid.x = 32 row-tiles; grid.y selects (P0,C0)/(P1,C1) for fused u/v.
// ---------------------------------------------------------------------------
template <int K>
__global__ __launch_bounds__(512, 4) void node_mfma(
    const float* __restrict__ A, const bf16x8* __restrict__ P0,
    const bf16x8* __restrict__ P1, const float* __restrict__ bias,
    int do_relu, float* __restrict__ C0, float* __restrict__ C1) {
  constexpr int KB = K / 16;                 // kb-steps
  constexpr int KH = K / 2;                  // col-pairs per row
  __shared__ __align__(16) char sA[32 * K * 2];

  int row0 = blockIdx.x * 32;
  const bf16x8* P = blockIdx.y ? P1 : P0;
  float* C = blockIdx.y ? C1 : C0;
  int tid = threadIdx.x, lane = tid & 63, w = tid >> 6;

  // ---- stage A tile: fp32 -> bf16, swizzled ----
  {
    int k2 = tid & (KH - 1);                 // fixed col-pair
    int rof = tid / KH;                      // row offset within iter
    constexpr int RPI = 512 / KH;            // rows per iteration
#pragma unroll 4
    for (int it = 0; it < 32 / RPI; it++) {
      int r = it * RPI + rof;
      float2 aa = *(const float2*)(A + (row0 + r) * K + 2 * k2);
      unsigned short s0 = __builtin_bit_cast(unsigned short, (__bf16)aa.x);
      unsigned short s1 = __builtin_bit_cast(unsigned short, (__bf16)aa.y);
      unsigned int pk = ((unsigned int)s1 << 16) | (unsigned int)s0;
      int wbyte = r * (2 * K) + ((4 * k2) ^ ((r & 15) << 4));
      *(unsigned int*)(sA + wbyte) = pk;
    }
  }
  __syncthreads();

  int arow = lane & 31;                      // rows 0..31
  int sAk = (arow & 15) << 4;
  int klo = (lane >> 5) * 8;

  const bf16x8* B0 = P + ((2 * w + 0) * KB) * 64 + lane;
  const bf16x8* B1 = P + ((2 * w + 1) * KB) * 64 + lane;

  f32x16 acc0, acc1;
#pragma unroll
  for (int r = 0; r < 16; r++) { acc0[r] = 0.f; acc1[r] = 0.f; }

#pragma unroll 2
  for (int kb = 0; kb < KB; kb++) {
    int abyte = arow * (2 * K) + (((kb * 16 + klo) * 2) ^ sAk);
    bf16x8 a = *(const bf16x8*)(sA + abyte);
    bf16x8 b0 = B0[kb * 64];
    bf16x8 b1 = B1[kb * 64];
    acc0 = __builtin_amdgcn_mfma_f32_32x32x16_bf16(a, b0, acc0, 0, 0, 0);
    acc1 = __builtin_amdgcn_mfma_f32_32x32x16_bf16(a, b1, acc1, 0, 0, 0);
  }

  // ---- epilogue: bias / relu, fp32 store (proven C layout, mrow=0) ----
#pragma unroll
  for (int blk = 0; blk < 2; blk++) {
    int cn = (2 * w + blk) * 32 + (lane & 31);
    float bv = bias ? bias[cn] : 0.f;
    const f32x16& A_ = blk ? acc1 : acc0;
#pragma unroll
    for (int r = 0; r < 16; r++) {
      int rr = (r & 3) + 8 * (r >> 2) + 4 * (lane >> 5);
      float val = A_[r] + bv;
      if (do_relu) val = fmaxf(val, 0.f);
      C[(row0 + rr) * 512 + cn] = val;
    }
  }
}

// ---------------------------------------------------------------------------
// Fused edge kernel — round-8 PASSING kernel, verbatim (best: 205 us,
// 670 TF = 98% of the measured 2-phase plain-HIP structural ceiling).
// LDS-staged B double-buffer via global_load_lds; two-tile B sharing.
// LDS 160 KB: h tiles 2x64 KB @0/@65536, B dbuf 2x16 KB @131072.
// ---------------------------------------------------------------------------
__global__ __launch_bounds__(512, 2) void edge_kernel(
    const float* __restrict__ u, const float* __restrict__ v,
    const bf16x8* __restrict__ Pb, const bf16x8* __restrict__ Pc,
    const float* __restrict__ bca, const float* __restrict__ bcb,
    const float* __restrict__ bcc, const float* __restrict__ Wo,
    const float* __restrict__ bo, float* __restrict__ out) {
  __shared__ __align__(16) char h_raw[163840];
  char* Bst = h_raw + 131072;

  int wg = blockIdx.x;                 // b*128 + i
  int i = wg & 127, b = wg >> 7;
  int tid = threadIdx.x, lane = tid & 63, w = tid >> 6;

  int mrow = (w & 1) * 32;
  int n0 = (w >> 1) * 128;
  int cg4 = (w >> 1) * 4;              // first col-block this wave consumes
  int arow = mrow + (lane & 31);
  int sA = (arow & 15) << 4;
  int klo = (lane >> 5) * 8;
  int cb0 = 2 * w;                     // col-block chunks this wave stages

#define STAGE_B(P, kb, sel)                                                       \
  {                                                                               \
    const char* _g0 = (const char*)((P) + (cb0 * 32 + (kb)) * 64) + lane * 16;    \
    const char* _g1 = (const char*)((P) + ((cb0 + 1) * 32 + (kb)) * 64) + lane * 16; \
    GLOAD_LDS16(_g0, Bst + (sel) * 16384 + cb0 * 1024);                           \
    GLOAD_LDS16(_g1, Bst + (sel) * 16384 + (cb0 + 1) * 1024);                     \
  }

  // stage GEMM1 kb=0 into buf0 now — lands during phase 1
  STAGE_B(Pb, 0, 0)

  // ---- phase 1: h1 = relu(u[j] + v[i] + bca) for j = 0..127 ----
  {
    int k2 = tid & 255;                                    // fixed col-pair
    float2 vv = *(const float2*)(v + (b * 128 + i) * 512 + 2 * k2);
    float2 bc = *(const float2*)(bca + 2 * k2);
    float vb0 = vv.x + bc.x, vb1 = vv.y + bc.y;
    const float* ub = u + (b * 128) * 512;
#pragma unroll 4
    for (int it = 0; it < 64; it++) {
      int r = it * 2 + (tid >> 8);                         // 0..127
      float2 uu = *(const float2*)(ub + r * 512 + 2 * k2);
      float x0 = fmaxf(uu.x + vb0, 0.f);
      float x1 = fmaxf(uu.y + vb1, 0.f);
      unsigned short s0 = __builtin_bit_cast(unsigned short, (__bf16)x0);
      unsigned short s1 = __builtin_bit_cast(unsigned short, (__bf16)x1);
      unsigned int pk = ((unsigned int)s1 << 16) | (unsigned int)s0;
      int rt = r & 63;
      int wbyte = ((r >> 6) << 16) + rt * 1024 + ((4 * k2) ^ ((rt & 15) << 4));
      *(unsigned int*)(h_raw + wbyte) = pk;
    }
  }
  __syncthreads();   // h ready + buf0 staged (implicit vmcnt(0) drain)

  f32x16 acc0[4], acc1[4];             // tile 0 / tile 1

  // ---- GEMM 1: h2 = h1 @ Wcb (B from LDS double-buffer) ----
#pragma unroll
  for (int nb = 0; nb < 4; nb++)
#pragma unroll
    for (int r = 0; r < 16; r++) { acc0[nb][r] = 0.f; acc1[nb][r] = 0.f; }
#pragma unroll 2
  for (int kb = 0; kb < 32; kb++) {
    int sel = kb & 1;
    if (kb < 31) STAGE_B(Pb, kb + 1, sel ^ 1)
    const char* bb = Bst + sel * 16384 + lane * 16;
    bf16x8 b0 = *(const bf16x8*)(bb + (cg4 + 0) * 1024);
    bf16x8 b1 = *(const bf16x8*)(bb + (cg4 + 1) * 1024);
    bf16x8 b2 = *(const bf16x8*)(bb + (cg4 + 2) * 1024);
    bf16x8 b3 = *(const bf16x8*)(bb + (cg4 + 3) * 1024);
    int abyte = arow * 1024 + (((kb * 16 + klo) * 2) ^ sA);
    bf16x8 a0 = *(const bf16x8*)(h_raw + abyte);
    bf16x8 a1 = *(const bf16x8*)(h_raw + 65536 + abyte);
    acc0[0] = __builtin_amdgcn_mfma_f32_32x32x16_bf16(a0, b0, acc0[0], 0, 0, 0);
    acc1[0] = __builtin_amdgcn_mfma_f32_32x32x16_bf16(a1, b0, acc1[0], 0, 0, 0);
    acc0[1] = __builtin_amdgcn_mfma_f32_32x32x16_bf16(a0, b1, acc0[1], 0, 0, 0);
    acc1[1] = __builtin_amdgcn_mfma_f32_32x32x16_bf16(a1, b1, acc1[1], 0, 0, 0);
    acc0[2] = __builtin_amdgcn_mfma_f32_32x32x16_bf16(a0, b2, acc0[2], 0, 0, 0);
    acc1[2] = __builtin_amdgcn_mfma_f32_32x32x16_bf16(a1, b2, acc1[2], 0, 0, 0);
    acc0[3] = __builtin_amdgcn_mfma_f32_32x32x16_bf16(a0, b3, acc0[3], 0, 0, 0);
    acc1[3] = __builtin_amdgcn_mfma_f32_32x32x16_bf16(a1, b3, acc1[3], 0, 0, 0);
    __syncthreads();               // buf[sel] reads done; buf[sel^1] staged
  }
  // cur parity back to 0; buf0's last readers were kb=30 (2 barriers ago)
  STAGE_B(Pc, 0, 0)                // lands during epilogue 1

  // ---- epilogue 1: h2 = relu(acc + bcb) -> bf16 LDS (swizzled), both tiles ----
#pragma unroll
  for (int nb = 0; nb < 4; nb++) {
    int cn = n0 + nb * 32 + (lane & 31);
    float bbv = bcb[cn];
#pragma unroll
    for (int r = 0; r < 16; r++) {
      int row = mrow + (r & 3) + 8 * (r >> 2) + 4 * (lane >> 5);
      int byte_ = row * 1024 + ((cn * 2) ^ ((row & 15) << 4));
      *(__bf16*)(h_raw + byte_) = (__bf16)fmaxf(acc0[nb][r] + bbv, 0.f);
      *(__bf16*)(h_raw + 65536 + byte_) = (__bf16)fmaxf(acc1[nb][r] + bbv, 0.f);
    }
  }
  __syncthreads();                 // h2 ready + Pc buf0 staged

  // ---- GEMM 2: h3 = h2 @ Wcc (B from LDS double-buffer) ----
#pragma unroll
  for (int nb = 0; nb < 4; nb++)
#pragma unroll
    for (int r = 0; r < 16; r++) { acc0[nb][r] = 0.f; acc1[nb][r] = 0.f; }
#pragma unroll 2
  for (int kb = 0; kb < 32; kb++) {
    int sel = kb & 1;
    if (kb < 31) STAGE_B(Pc, kb + 1, sel ^ 1)
    const char* bb = Bst + sel * 16384 + lane * 16;
    bf16x8 b0 = *(const bf16x8*)(bb + (cg4 + 0) * 1024);
    bf16x8 b1 = *(const bf16x8*)(bb + (cg4 + 1) * 1024);
    bf16x8 b2 = *(const bf16x8*)(bb + (cg4 + 2) * 1024);
    bf16x8 b3 = *(const bf16x8*)(bb + (cg4 + 3) * 1024);
    int abyte = arow * 1024 + (((kb * 16 + klo) * 2) ^ sA);
    bf16x8 a0 = *(const bf16x8*)(h_raw + abyte);
    bf16x8 a1 = *(const bf16x8*)(h_raw + 65536 + abyte);
    acc0[0] = __builtin_amdgcn_mfma_f32_32x32x16_bf16(a0, b0, acc0[0], 0, 0, 0);
    acc1[0] = __builtin_amdgcn_mfma_f32_32x32x16_bf16(a1, b0, acc1[0], 0, 0, 0);
    acc0[1] = __builtin_amdgcn_mfma_f32_32x32x16_bf16(a0, b1, acc0[1], 0, 0, 0);
    acc1[1] = __builtin_amdgcn_mfma_f32_32x32x16_bf16(a1, b1, acc1[1], 0, 0, 0);
    acc0[2] = __builtin_amdgcn_mfma_f32_32x32x16_bf16(a0, b2, acc0[2], 0, 0, 0);
    acc1[2] = __builtin_amdgcn_mfma_f32_32x32x16_bf16(a1, b2, acc1[2], 0, 0, 0);
    acc0[3] = __builtin_amdgcn_mfma_f32_32x32x16_bf16(a0, b3, acc0[3], 0, 0, 0);
    acc1[3] = __builtin_amdgcn_mfma_f32_32x32x16_bf16(a1, b3, acc1[3], 0, 0, 0);
    __syncthreads();
  }

  // ---- epilogue 2: h3 = relu(acc + bcc); fold Wo; shfl-reduce (fp32) ----
  float p0[16][2] = {}, p1[16][2] = {};
#pragma unroll
  for (int nb = 0; nb < 4; nb++) {
    int cn = n0 + nb * 32 + (lane & 31);
    float bcv = bcc[cn];
    float2 wov = *(const float2*)(Wo + cn * 2);
#pragma unroll
    for (int r = 0; r < 16; r++) {
      float h30 = fmaxf(acc0[nb][r] + bcv, 0.f);
      float h31 = fmaxf(acc1[nb][r] + bcv, 0.f);
      p0[r][0] += h30 * wov.x; p0[r][1] += h30 * wov.y;
      p1[r][0] += h31 * wov.x; p1[r][1] += h31 * wov.y;
    }
  }
#pragma unroll
  for (int m = 1; m <= 16; m <<= 1) {
#pragma unroll
    for (int r = 0; r < 16; r++) {
      p0[r][0] += __shfl_xor(p0[r][0], m, 64);
      p0[r][1] += __shfl_xor(p0[r][1], m, 64);
      p1[r][0] += __shfl_xor(p1[r][0], m, 64);
      p1[r][1] += __shfl_xor(p1[r][1], m, 64);
    }
  }
  __syncthreads();                 // all GEMM2 LDS reads done; reuse h_raw
  float* red = (float*)h_raw;      // [4 colgroups][128 rows][2] = 4 KB
  if ((lane & 31) == 0) {
    int hh = lane >> 5, cg = w >> 1;
#pragma unroll
    for (int r = 0; r < 16; r++) {
      int row = mrow + (r & 3) + 8 * (r >> 2) + 4 * hh;
      red[(cg * 128 + row) * 2 + 0] = p0[r][0];
      red[(cg * 128 + row) * 2 + 1] = p0[r][1];
      red[(cg * 128 + 64 + row) * 2 + 0] = p1[r][0];
      red[(cg * 128 + 64 + row) * 2 + 1] = p1[r][1];
    }
  }
  __syncthreads();
  if (tid < 256) {
    int row = tid >> 1, d = tid & 1;
    float s = red[(0 * 128 + row) * 2 + d] + red[(1 * 128 + row) * 2 + d] +
              red[(2 * 128 + row) * 2 + d] + red[(3 * 128 + row) * 2 + d] + bo[d];
    out[((b * 128 + i) * 128 + row) * 2 + d] = s;
  }
#undef STAGE_B
}

// ---------------------------------------------------------------------------
extern "C" void kernel_launch(void* const* d_in, const int* in_sizes, int n_in,
                              void* d_out, int out_size, void* d_ws, size_t ws_size,
                              hipStream_t stream) {
  const float* x   = (const float*)d_in[0];
  const float* Wa  = (const float*)d_in[1];
  const float* ba  = (const float*)d_in[2];
  const float* Wb  = (const float*)d_in[3];
  const float* bb  = (const float*)d_in[4];
  const float* Wca = (const float*)d_in[5];
  const float* bca = (const float*)d_in[6];
  const float* Wcb = (const float*)d_in[7];
  const float* bcb = (const float*)d_in[8];
  const float* Wcc = (const float*)d_in[9];
  const float* bcc = (const float*)d_in[10];
  const float* Wo  = (const float*)d_in[11];
  const float* bo  = (const float*)d_in[12];
  float* out = (float*)d_out;

  char* ws = (char*)d_ws;
  float* f1 = (float*)(ws);                                 // 2 MB
  float* f  = (float*)(ws + (2u << 20));                    // 2 MB
  float* u  = (float*)(ws + (4u << 20));                    // 2 MB
  float* v  = (float*)(ws + (6u << 20));                    // 2 MB
  __bf16* Pb  = (__bf16*)(ws + (8u << 20));                 // 512 KB
  __bf16* Pc  = (__bf16*)(ws + (8u << 20) + (512u << 10));  // 512 KB
  __bf16* PWb = (__bf16*)(ws + (9u << 20));                 // 512 KB
  __bf16* PH0 = (__bf16*)(ws + (9u << 20) + (512u << 10));  // 512 KB
  __bf16* PH1 = (__bf16*)(ws + (10u << 20));                // 512 KB
  __bf16* PWa = (__bf16*)(ws + (10u << 20) + (512u << 10)); // 256 KB

  pack_all<<<5632, 256, 0, stream>>>(Wcb, Wcc, Wb, Wca, Wa,
                                     Pb, Pc, PWb, PH0, PH1, PWa);
  // node MLP in bf16 MFMA (fp32 accumulate), 32-row tiles:
  node_mfma<256><<<dim3(32, 1), 512, 0, stream>>>(
      x, (const bf16x8*)PWa, (const bf16x8*)PWa, ba, 1, f1, f1);
  node_mfma<512><<<dim3(32, 1), 512, 0, stream>>>(
      f1, (const bf16x8*)PWb, (const bf16x8*)PWb, bb, 1, f, f);
  node_mfma<512><<<dim3(32, 2), 512, 0, stream>>>(
      f, (const bf16x8*)PH0, (const bf16x8*)PH1, nullptr, 0, u, v);
  // fused edge MLP (round-8 kernel, unchanged)
  edge_kernel<<<1024, 512, 0, stream>>>(u, v, (const bf16x8*)Pb, (const bf16x8*)Pc,
                                        bca, bcb, bcc, Wo, bo, out);
}